// Round 1
// baseline (30.691 us; speedup 1.0000x reference)
//
#include <hip/hip_runtime.h>

// RegularizationLoss: out = mean_b( ||M1 M1^T - I||_F^2 + ||M2 M2^T - I||_F^2 )
// input: (2000000, 6, 3) f32; M1 = rows 0..2, M2 = rows 3..5.
// Memory-bound streaming reduction: 144 MB read -> scalar.

#define NBLK 1024
#define NTHR 256

__global__ __launch_bounds__(NTHR) void reg_loss_partial(
    const float4* __restrict__ in4, float* __restrict__ partial, int npairs) {
    int tid = blockIdx.x * NTHR + threadIdx.x;
    const int stride = NBLK * NTHR;
    float acc = 0.0f;

    for (int p = tid; p < npairs; p += stride) {
        // one pair = 2 batches = 36 floats = 9 float4 (16B-aligned: 144 B per pair)
        float4 v[9];
        #pragma unroll
        for (int k = 0; k < 9; ++k) v[k] = in4[(size_t)p * 9 + k];

        float m[36];
        #pragma unroll
        for (int k = 0; k < 9; ++k) {
            m[4 * k + 0] = v[k].x;
            m[4 * k + 1] = v[k].y;
            m[4 * k + 2] = v[k].z;
            m[4 * k + 3] = v[k].w;
        }

        #pragma unroll
        for (int b = 0; b < 2; ++b) {
            const float* batch = m + b * 18;
            // two 3x3 matrices per batch: M1 = batch[0..8], M2 = batch[9..17]
            #pragma unroll
            for (int h = 0; h < 2; ++h) {
                const float* M = batch + h * 9;
                // A = M M^T - I is symmetric: diag once, off-diag x2
                #pragma unroll
                for (int i = 0; i < 3; ++i) {
                    #pragma unroll
                    for (int j = i; j < 3; ++j) {
                        float d = M[3 * i + 0] * M[3 * j + 0]
                                + M[3 * i + 1] * M[3 * j + 1]
                                + M[3 * i + 2] * M[3 * j + 2]
                                - (i == j ? 1.0f : 0.0f);
                        acc += (i == j) ? d * d : 2.0f * d * d;
                    }
                }
            }
        }
    }

    // wave64 reduction
    #pragma unroll
    for (int off = 32; off > 0; off >>= 1) acc += __shfl_down(acc, off, 64);

    __shared__ float wsum[NTHR / 64];
    const int lane = threadIdx.x & 63;
    const int wid  = threadIdx.x >> 6;
    if (lane == 0) wsum[wid] = acc;
    __syncthreads();
    if (threadIdx.x == 0) {
        float s = 0.0f;
        #pragma unroll
        for (int w = 0; w < NTHR / 64; ++w) s += wsum[w];
        partial[blockIdx.x] = s;
    }
}

__global__ __launch_bounds__(256) void reg_loss_final(
    const float* __restrict__ partial, float* __restrict__ out, int nb, float invN) {
    float acc = 0.0f;
    for (int i = threadIdx.x; i < nb; i += 256) acc += partial[i];
    #pragma unroll
    for (int off = 32; off > 0; off >>= 1) acc += __shfl_down(acc, off, 64);

    __shared__ float wsum[4];
    const int lane = threadIdx.x & 63;
    const int wid  = threadIdx.x >> 6;
    if (lane == 0) wsum[wid] = acc;
    __syncthreads();
    if (threadIdx.x == 0) {
        out[0] = (wsum[0] + wsum[1] + wsum[2] + wsum[3]) * invN;
    }
}

extern "C" void kernel_launch(void* const* d_in, const int* in_sizes, int n_in,
                              void* d_out, int out_size, void* d_ws, size_t ws_size,
                              hipStream_t stream) {
    const float* in = (const float*)d_in[0];
    float* out = (float*)d_out;
    float* partial = (float*)d_ws;  // NBLK floats of scratch

    const int total_floats = in_sizes[0];      // 2000000 * 6 * 3 = 36,000,000
    const int nbatch = total_floats / 18;      // 2,000,000
    const int npairs = total_floats / 36;      // 1,000,000 (even batch count)

    reg_loss_partial<<<NBLK, NTHR, 0, stream>>>((const float4*)in, partial, npairs);
    reg_loss_final<<<1, 256, 0, stream>>>(partial, out, NBLK, 1.0f / (float)nbatch);
}